// Round 6
// baseline (68.782 us; speedup 1.0000x reference)
//
#include <hip/hip_runtime.h>

// out[m, n] = sum_d a[m, d] * T_d(x[n]),  T_d = Chebyshev via recurrence.
// N = 2097152, M = 32, DEG = 16. Write-BW-bound (~256 MiB out).
// R5: R0 structure (EPT=4, float4 stores — R4 proved 8B stores cost ~6us)
// + per-wave rotation of the m-loop start phase. Theory: all 32 stores of a
// wave go to base + m*8MB + i with the same i -> same HBM channel phase,
// bursty per-channel hotspots. Rotating m per wave spreads instantaneous
// store traffic across all 32 streams/channels. Only change vs R0.

#define DEG 16
#define M_ROWS 32
#define ELEMS_PER_THREAD 4

__global__ __launch_bounds__(256) void cheb_gemm_kernel(
    const float* __restrict__ x,
    const float* __restrict__ a,
    float* __restrict__ out,
    int n)
{
    const int i = (blockIdx.x * 256 + threadIdx.x) * ELEMS_PER_THREAD;
    if (i + ELEMS_PER_THREAD - 1 >= n) return;

    // Coalesced 16B load of 4 consecutive x values.
    const float4 xv = *reinterpret_cast<const float4*>(x + i);
    float xs[ELEMS_PER_THREAD] = {xv.x, xv.y, xv.z, xv.w};

    // Chebyshev basis T_0..T_15 for each of the 4 elements, in registers.
    float basis[ELEMS_PER_THREAD][DEG];
#pragma unroll
    for (int j = 0; j < ELEMS_PER_THREAD; ++j) {
        float t0 = 1.0f;
        float t1 = xs[j];
        basis[j][0] = t0;
        basis[j][1] = t1;
        const float two_x = xs[j] + xs[j];
#pragma unroll
        for (int k = 2; k < DEG; ++k) {
            float t2 = fmaf(two_x, t1, -t0);
            basis[j][k] = t2;
            t0 = t1;
            t1 = t2;
        }
    }

    // Wave-uniform m-phase rotation: concurrent waves hit different m-streams.
    const int wave_id = threadIdx.x >> 6;
    const int phase = (blockIdx.x * 4 + wave_id) & (M_ROWS - 1);

#pragma unroll 4
    for (int mm = 0; mm < M_ROWS; ++mm) {
        const int m = (mm + phase) & (M_ROWS - 1);  // wave-uniform
        float acc0 = 0.0f, acc1 = 0.0f, acc2 = 0.0f, acc3 = 0.0f;
#pragma unroll
        for (int d = 0; d < DEG; ++d) {
            const float c = a[m * DEG + d];  // wave-uniform -> scalar load
            acc0 = fmaf(c, basis[0][d], acc0);
            acc1 = fmaf(c, basis[1][d], acc1);
            acc2 = fmaf(c, basis[2][d], acc2);
            acc3 = fmaf(c, basis[3][d], acc3);
        }
        float4* dst = reinterpret_cast<float4*>(out + (size_t)m * (size_t)n + i);
        *dst = make_float4(acc0, acc1, acc2, acc3);
    }
}

extern "C" void kernel_launch(void* const* d_in, const int* in_sizes, int n_in,
                              void* d_out, int out_size, void* d_ws, size_t ws_size,
                              hipStream_t stream) {
    const float* x = (const float*)d_in[0];
    const float* a = (const float*)d_in[1];
    float* out = (float*)d_out;
    const int n = in_sizes[0];  // 2097152

    const int threads = 256;
    const int elems_per_block = threads * ELEMS_PER_THREAD;  // 1024
    const int blocks = (n + elems_per_block - 1) / elems_per_block;  // 2048

    cheb_gemm_kernel<<<blocks, threads, 0, stream>>>(x, a, out, n);
}

// Round 7
// 56.191 us; speedup vs baseline: 1.2241x; 1.2241x over previous
//
#include <hip/hip_runtime.h>

// out[m, n] = sum_d a[m, d] * T_d(x[n]),  T_d = Chebyshev via recurrence.
// N = 2097152, M = 32, DEG = 16. Write-BW-bound (~256 MiB out).
// R6: R0 structure EXACTLY (EPT=4, float4 stores, m-ascending store order —
// R3/R5 proved spreading concurrent stores across m-streams costs ~16 us,
// R2 proved NT costs ~15 us, R4 proved 8B stores cost ~6 us).
// Single change: halve dot-product VALU via v_pk_fma_f32 over j-pairs.
// Coefficient broadcast {c,c} comes from a 4 KB a_dup table in d_ws
// (built by a setup kernel) so it can be a wave-uniform SGPR-pair source.

#define DEG 16
#define M_ROWS 32
#define ELEMS_PER_THREAD 4

typedef __attribute__((ext_vector_type(2))) float f32x2;

__global__ __launch_bounds__(512) void dup_coeff_kernel(
    const float* __restrict__ a, f32x2* __restrict__ ad)
{
    const int i = threadIdx.x;  // 0..511 = M_ROWS*DEG
    if (i < M_ROWS * DEG) {
        const float c = a[i];
        f32x2 v; v.x = c; v.y = c;
        ad[i] = v;
    }
}

__global__ __launch_bounds__(256) void cheb_gemm_kernel(
    const float* __restrict__ x,
    const f32x2* __restrict__ ad,   // a_dup[m*DEG+d] = {a[m][d], a[m][d]}
    float* __restrict__ out,
    int n)
{
    const int i = (blockIdx.x * 256 + threadIdx.x) * ELEMS_PER_THREAD;
    if (i + ELEMS_PER_THREAD - 1 >= n) return;

    const float4 xv = *reinterpret_cast<const float4*>(x + i);

    // Basis pairs: bA[d] = {T_d(x0), T_d(x1)}, bB[d] = {T_d(x2), T_d(x3)}.
    f32x2 bA[DEG], bB[DEG];
    {
        f32x2 xA; xA.x = xv.x; xA.y = xv.y;
        f32x2 xB; xB.x = xv.z; xB.y = xv.w;
        f32x2 one; one.x = 1.0f; one.y = 1.0f;
        bA[0] = one; bB[0] = one;
        bA[1] = xA;  bB[1] = xB;
        const f32x2 txA = xA + xA;
        const f32x2 txB = xB + xB;
#pragma unroll
        for (int k = 2; k < DEG; ++k) {
            bA[k] = txA * bA[k - 1] - bA[k - 2];  // v_pk_fma_f32
            bB[k] = txB * bB[k - 1] - bB[k - 2];
        }
    }

    // Per m-row: packed dot product, coefficients as SGPR-pair broadcasts.
#pragma unroll 4
    for (int m = 0; m < M_ROWS; ++m) {
        const f32x2* cm = ad + m * DEG;  // wave-uniform -> s_load
        f32x2 accA, accB;
        {
            const f32x2 c0 = cm[0];
            asm("v_pk_mul_f32 %0, %1, %2" : "=v"(accA) : "s"(c0), "v"(bA[0]));
            asm("v_pk_mul_f32 %0, %1, %2" : "=v"(accB) : "s"(c0), "v"(bB[0]));
        }
#pragma unroll
        for (int d = 1; d < DEG; ++d) {
            const f32x2 cd = cm[d];
            asm("v_pk_fma_f32 %0, %1, %2, %0" : "+v"(accA) : "s"(cd), "v"(bA[d]));
            asm("v_pk_fma_f32 %0, %1, %2, %0" : "+v"(accB) : "s"(cd), "v"(bB[d]));
        }
        float4* dst = reinterpret_cast<float4*>(out + (size_t)m * (size_t)n + i);
        *dst = make_float4(accA.x, accA.y, accB.x, accB.y);
    }
}

extern "C" void kernel_launch(void* const* d_in, const int* in_sizes, int n_in,
                              void* d_out, int out_size, void* d_ws, size_t ws_size,
                              hipStream_t stream) {
    const float* x = (const float*)d_in[0];
    const float* a = (const float*)d_in[1];
    float* out = (float*)d_out;
    const int n = in_sizes[0];  // 2097152

    f32x2* ad = (f32x2*)d_ws;  // needs M_ROWS*DEG*8 = 4096 bytes
    dup_coeff_kernel<<<1, 512, 0, stream>>>(a, ad);

    const int threads = 256;
    const int elems_per_block = threads * ELEMS_PER_THREAD;  // 1024
    const int blocks = (n + elems_per_block - 1) / elems_per_block;  // 2048

    cheb_gemm_kernel<<<blocks, threads, 0, stream>>>(x, ad, out, n);
}

// Round 8
// 48.271 us; speedup vs baseline: 1.4249x; 1.1641x over previous
//
#include <hip/hip_runtime.h>

// out[m, n] = sum_d a[m, d] * T_d(x[n]),  T_d = Chebyshev via recurrence.
// N = 2097152, M = 32, DEG = 16. Write-BW-bound (~256 MiB out).
// R7: R0 EXACTLY (EPT=4, float4 stores, m-ascending order, scalar FMA dot —
// R2/R3/R4/R5/R6 proved nt / spread / narrow stores / pk+extra-dispatch all
// regress) + ONE change: XCD-contiguous blockIdx swizzle. Default round-robin
// gives each XCD's L2 a 4KB-grain interleaved write stream (32KB-stride
// holes); remapping so each XCD owns a contiguous 1MB slice per row makes
// each per-XCD writeback stream linear, like the 6.9 TB/s fill kernel's.

#define DEG 16
#define M_ROWS 32
#define ELEMS_PER_THREAD 4
#define NUM_XCD 8

__global__ __launch_bounds__(256) void cheb_gemm_kernel(
    const float* __restrict__ x,
    const float* __restrict__ a,
    float* __restrict__ out,
    int n)
{
    // Bijective XCD swizzle (gridDim.x % 8 == 0): block b runs on XCD (b%8);
    // give it the (b%8)-th contiguous chunk-range so each XCD writes a
    // contiguous slice of the n-dimension.
    const int per_xcd = gridDim.x >> 3;               // 256
    const int chunk = (blockIdx.x & (NUM_XCD - 1)) * per_xcd
                    + (blockIdx.x >> 3);
    const int i = (chunk * 256 + threadIdx.x) * ELEMS_PER_THREAD;
    if (i + ELEMS_PER_THREAD - 1 >= n) return;

    // Coalesced 16B load of 4 consecutive x values.
    const float4 xv = *reinterpret_cast<const float4*>(x + i);
    float xs[ELEMS_PER_THREAD] = {xv.x, xv.y, xv.z, xv.w};

    // Chebyshev basis T_0..T_15 for each of the 4 elements, in registers.
    float basis[ELEMS_PER_THREAD][DEG];
#pragma unroll
    for (int j = 0; j < ELEMS_PER_THREAD; ++j) {
        float t0 = 1.0f;
        float t1 = xs[j];
        basis[j][0] = t0;
        basis[j][1] = t1;
        const float two_x = xs[j] + xs[j];
#pragma unroll
        for (int k = 2; k < DEG; ++k) {
            float t2 = fmaf(two_x, t1, -t0);
            basis[j][k] = t2;
            t0 = t1;
            t1 = t2;
        }
    }

    // For each output row m: dot(a[m, :], basis[j, :]) then float4 store.
    // a[] addresses are wave-uniform -> scalar loads.
#pragma unroll 4
    for (int m = 0; m < M_ROWS; ++m) {
        float acc0 = 0.0f, acc1 = 0.0f, acc2 = 0.0f, acc3 = 0.0f;
#pragma unroll
        for (int d = 0; d < DEG; ++d) {
            const float c = a[m * DEG + d];
            acc0 = fmaf(c, basis[0][d], acc0);
            acc1 = fmaf(c, basis[1][d], acc1);
            acc2 = fmaf(c, basis[2][d], acc2);
            acc3 = fmaf(c, basis[3][d], acc3);
        }
        float4* dst = reinterpret_cast<float4*>(out + (size_t)m * (size_t)n + i);
        *dst = make_float4(acc0, acc1, acc2, acc3);
    }
}

extern "C" void kernel_launch(void* const* d_in, const int* in_sizes, int n_in,
                              void* d_out, int out_size, void* d_ws, size_t ws_size,
                              hipStream_t stream) {
    const float* x = (const float*)d_in[0];
    const float* a = (const float*)d_in[1];
    float* out = (float*)d_out;
    const int n = in_sizes[0];  // 2097152

    const int threads = 256;
    const int elems_per_block = threads * ELEMS_PER_THREAD;  // 1024
    const int blocks = (n + elems_per_block - 1) / elems_per_block;  // 2048

    cheb_gemm_kernel<<<blocks, threads, 0, stream>>>(x, a, out, n);
}